// Round 1
// baseline (93.563 us; speedup 1.0000x reference)
//
#include <hip/hip_runtime.h>
#include <math.h>

#define B_   4
#define N_   512
#define DIN  256
#define E_   64
#define H_   4

// ---------------------------------------------------------------------------
// Projection kernel: per block computes Y[64 rows][64 cols] = X_tile * W + b
// grid = B*H*3*(N/64) = 384 blocks, 256 threads.
// p=0 -> Q [B][H][N][E], p=1 -> KT [B][H][E][N] (transposed), p=2 -> V.
// ---------------------------------------------------------------------------
__global__ __launch_bounds__(256) void proj_kernel(
    const float* __restrict__ x,
    const float* __restrict__ Wq, const float* __restrict__ bq,
    const float* __restrict__ Wk, const float* __restrict__ bk,
    const float* __restrict__ Wv, const float* __restrict__ bv,
    float* __restrict__ Q, float* __restrict__ KT, float* __restrict__ V)
{
    const int tid = threadIdx.x;
    int blk = blockIdx.x;
    const int tile = blk & 7;  blk >>= 3;
    const int p    = blk % 3;  blk /= 3;
    const int h    = blk & 3;
    const int b    = blk >> 2;

    const float* W;
    const float* bias;
    if (p == 0)      { W = Wq; bias = bq; }
    else if (p == 1) { W = Wk; bias = bk; }
    else             { W = Wv; bias = bv; }
    W    += (size_t)h * DIN * E_;
    bias += h * E_;

    const int rowbase = tile * 64;
    const float* xb = x + ((size_t)b * N_ + rowbase) * DIN;

    __shared__ float Xs[64][65];   // +1 pad: rows 4 apart -> bank +4, conflict-free
    __shared__ float Ws[64][68];   // +4 pad: keeps float4 alignment, spreads banks

    const int tr = tid >> 4;   // 0..15 (row group)
    const int tc = tid & 15;   // 0..15 (col group)

    float acc[4][4];
    #pragma unroll
    for (int i = 0; i < 4; ++i)
        #pragma unroll
        for (int j = 0; j < 4; ++j) acc[i][j] = 0.f;

    for (int dc = 0; dc < DIN; dc += 64) {
        for (int l = tid; l < 4096; l += 256) {
            int r = l >> 6, j = l & 63;
            Xs[r][j] = xb[r * DIN + dc + j];
        }
        for (int l = tid; l < 4096; l += 256) {
            int d = l >> 6, c = l & 63;
            Ws[d][c] = W[(size_t)(dc + d) * E_ + c];
        }
        __syncthreads();

        #pragma unroll 8
        for (int d = 0; d < 64; ++d) {
            float4 wv = *(const float4*)&Ws[d][tc * 4];
            float xv[4];
            #pragma unroll
            for (int i = 0; i < 4; ++i) xv[i] = Xs[tr * 4 + i][d];
            #pragma unroll
            for (int i = 0; i < 4; ++i) {
                acc[i][0] = fmaf(xv[i], wv.x, acc[i][0]);
                acc[i][1] = fmaf(xv[i], wv.y, acc[i][1]);
                acc[i][2] = fmaf(xv[i], wv.z, acc[i][2]);
                acc[i][3] = fmaf(xv[i], wv.w, acc[i][3]);
            }
        }
        __syncthreads();
    }

    const size_t bh = (size_t)b * H_ + h;
    float4 bias4 = *(const float4*)&bias[tc * 4];

    if (p == 1) {
        // K transposed: KT[b][h][e][n]
        float* o = KT + bh * (size_t)(E_ * N_);
        #pragma unroll
        for (int i = 0; i < 4; ++i) {
            int r = rowbase + tr * 4 + i;
            o[(size_t)(tc * 4 + 0) * N_ + r] = acc[i][0] + bias4.x;
            o[(size_t)(tc * 4 + 1) * N_ + r] = acc[i][1] + bias4.y;
            o[(size_t)(tc * 4 + 2) * N_ + r] = acc[i][2] + bias4.z;
            o[(size_t)(tc * 4 + 3) * N_ + r] = acc[i][3] + bias4.w;
        }
    } else {
        float* o = (p == 0 ? Q : V) + bh * (size_t)(N_ * E_);
        #pragma unroll
        for (int i = 0; i < 4; ++i) {
            int r = rowbase + tr * 4 + i;
            float4 val;
            val.x = acc[i][0] + bias4.x;
            val.y = acc[i][1] + bias4.y;
            val.z = acc[i][2] + bias4.z;
            val.w = acc[i][3] + bias4.w;
            *(float4*)&o[(size_t)r * E_ + tc * 4] = val;
        }
    }
}

// ---------------------------------------------------------------------------
// Attention kernel: per block one (b, h, 32-row q tile). grid = 256 blocks.
// Phase 1: logits[32][512] in LDS (thread owns key columns tid, tid+256).
// Phase 2: wave-parallel softmax. Phase 3: PV with float4 P reads.
// ---------------------------------------------------------------------------
template <int HEAD>
__device__ __forceinline__ void compute_logits(
    const float* __restrict__ KTbh, const float (*q_lds)[36],
    float (*P)[512], const float* __restrict__ kn, const float* __restrict__ qn,
    int tid)
{
    float acc0[32], acc1[32];
    #pragma unroll
    for (int r = 0; r < 32; ++r) { acc0[r] = 0.f; acc1[r] = 0.f; }

    const int m0 = tid;
    const int m1 = tid + 256;

    for (int e = 0; e < 64; ++e) {
        float k0 = KTbh[e * N_ + m0];
        float k1 = KTbh[e * N_ + m1];
        #pragma unroll
        for (int rq = 0; rq < 8; ++rq) {
            float4 qv = *(const float4*)&q_lds[e][rq * 4];
            float qa[4] = {qv.x, qv.y, qv.z, qv.w};
            #pragma unroll
            for (int j = 0; j < 4; ++j) {
                int r = rq * 4 + j;
                if (HEAD <= 1) {          // dot product (sdp / cosine)
                    acc0[r] = fmaf(qa[j], k0, acc0[r]);
                    acc1[r] = fmaf(qa[j], k1, acc1[r]);
                } else if (HEAD == 2) {   // L1
                    acc0[r] += fabsf(k0 - qa[j]);
                    acc1[r] += fabsf(k1 - qa[j]);
                } else {                  // L2 (squared, sqrt at the end)
                    float d0 = k0 - qa[j]; acc0[r] = fmaf(d0, d0, acc0[r]);
                    float d1 = k1 - qa[j]; acc1[r] = fmaf(d1, d1, acc1[r]);
                }
            }
        }
    }

    float ikn0 = 0.f, ikn1 = 0.f;
    if (HEAD == 1) { ikn0 = kn[m0]; ikn1 = kn[m1]; }  // inverse norms
    #pragma unroll
    for (int r = 0; r < 32; ++r) {
        float l0, l1;
        if (HEAD == 0)      { l0 = acc0[r] * 0.125f;        l1 = acc1[r] * 0.125f; }
        else if (HEAD == 1) { float iq = qn[r];
                              l0 = acc0[r] * iq * ikn0;     l1 = acc1[r] * iq * ikn1; }
        else if (HEAD == 2) { l0 = -acc0[r];                l1 = -acc1[r]; }
        else                { l0 = -sqrtf(acc0[r]);         l1 = -sqrtf(acc1[r]); }
        P[r][m0] = l0;
        P[r][m1] = l1;
    }
}

__global__ __launch_bounds__(256) void attn_kernel(
    const float* __restrict__ Q, const float* __restrict__ KT,
    const float* __restrict__ V, float* __restrict__ out)
{
    const int tid = threadIdx.x;
    int blk = blockIdx.x;
    const int qt = blk & 15; blk >>= 4;
    const int h  = blk & 3;
    const int b  = blk >> 2;

    const size_t bh = (size_t)b * H_ + h;
    const float* Qbh  = Q  + bh * (size_t)(N_ * E_) + (size_t)qt * 32 * E_;
    const float* KTbh = KT + bh * (size_t)(E_ * N_);
    const float* Vbh  = V  + bh * (size_t)(N_ * E_);

    __shared__ float q_lds[64][36];   // [e][r], 144B row stride (16B aligned)
    __shared__ float P[32][512];
    __shared__ float kn[512];
    __shared__ float qn[32];
    __shared__ float rinv[32];

    // stage q transposed into LDS
    for (int l = tid; l < 2048; l += 256) {
        int r = l >> 6, e = l & 63;
        q_lds[e][r] = Qbh[l];
    }
    __syncthreads();

    if (h == 1) {  // inverse norms for cosine head (block-uniform branch)
        if (tid < 32) {
            float s = 0.f;
            for (int e = 0; e < 64; ++e) { float v = q_lds[e][tid]; s = fmaf(v, v, s); }
            qn[tid] = 1.f / sqrtf(s);
        }
        for (int m = tid; m < 512; m += 256) {
            float s = 0.f;
            for (int e = 0; e < 64; ++e) { float t = KTbh[e * N_ + m]; s = fmaf(t, t, s); }
            kn[m] = 1.f / sqrtf(s);
        }
        __syncthreads();
    }

    if (h == 0)      compute_logits<0>(KTbh, q_lds, P, kn, qn, tid);
    else if (h == 1) compute_logits<1>(KTbh, q_lds, P, kn, qn, tid);
    else if (h == 2) compute_logits<2>(KTbh, q_lds, P, kn, qn, tid);
    else             compute_logits<3>(KTbh, q_lds, P, kn, qn, tid);
    __syncthreads();

    // softmax: wave w owns rows w*8 .. w*8+7
    {
        const int wv = tid >> 6, lane = tid & 63;
        #pragma unroll
        for (int rr = 0; rr < 8; ++rr) {
            int r = wv * 8 + rr;
            float vals[8];
            float mx = -1e30f;
            #pragma unroll
            for (int k = 0; k < 8; ++k) {
                vals[k] = P[r][lane + k * 64];
                mx = fmaxf(mx, vals[k]);
            }
            #pragma unroll
            for (int off = 32; off; off >>= 1) mx = fmaxf(mx, __shfl_xor(mx, off, 64));
            float s = 0.f;
            #pragma unroll
            for (int k = 0; k < 8; ++k) {
                float pv = __expf(vals[k] - mx);
                s += pv;
                P[r][lane + k * 64] = pv;
            }
            #pragma unroll
            for (int off = 32; off; off >>= 1) s += __shfl_xor(s, off, 64);
            if (lane == 0) rinv[r] = 1.f / s;
        }
    }
    __syncthreads();

    // PV: thread -> (row group, e); rows r = rgrp*8 + rr
    {
        const int rgrp = tid >> 6;
        const int e    = tid & 63;
        float acc[8];
        #pragma unroll
        for (int rr = 0; rr < 8; ++rr) acc[rr] = 0.f;

        for (int m = 0; m < N_; m += 4) {
            float v0 = Vbh[(size_t)(m + 0) * E_ + e];
            float v1 = Vbh[(size_t)(m + 1) * E_ + e];
            float v2 = Vbh[(size_t)(m + 2) * E_ + e];
            float v3 = Vbh[(size_t)(m + 3) * E_ + e];
            #pragma unroll
            for (int rr = 0; rr < 8; ++rr) {
                int r = rgrp * 8 + rr;
                float4 pp = *(const float4*)&P[r][m];
                acc[rr] = fmaf(pp.x, v0, acc[rr]);
                acc[rr] = fmaf(pp.y, v1, acc[rr]);
                acc[rr] = fmaf(pp.z, v2, acc[rr]);
                acc[rr] = fmaf(pp.w, v3, acc[rr]);
            }
        }

        #pragma unroll
        for (int rr = 0; rr < 8; ++rr) {
            int r = rgrp * 8 + rr;
            int n = qt * 32 + r;
            out[((size_t)b * N_ + n) * (H_ * E_) + h * E_ + e] = acc[rr] * rinv[r];
        }
    }
}

// ---------------------------------------------------------------------------
extern "C" void kernel_launch(void* const* d_in, const int* in_sizes, int n_in,
                              void* d_out, int out_size, void* d_ws, size_t ws_size,
                              hipStream_t stream)
{
    const float* x  = (const float*)d_in[0];
    const float* Wq = (const float*)d_in[1];
    const float* bq = (const float*)d_in[2];
    const float* Wk = (const float*)d_in[3];
    const float* bk = (const float*)d_in[4];
    const float* Wv = (const float*)d_in[5];
    const float* bv = (const float*)d_in[6];
    float* out = (float*)d_out;

    float* ws = (float*)d_ws;
    const size_t qkv = (size_t)B_ * H_ * N_ * E_;  // 524288 floats
    float* Q  = ws;
    float* KT = ws + qkv;
    float* V  = ws + 2 * qkv;

    proj_kernel<<<B_ * H_ * 3 * (N_ / 64), 256, 0, stream>>>(
        x, Wq, bq, Wk, bk, Wv, bv, Q, KT, V);
    attn_kernel<<<B_ * H_ * (N_ / 32), 256, 0, stream>>>(Q, KT, V, out);
}

// Round 2
// 66.255 us; speedup vs baseline: 1.4122x; 1.4122x over previous
//
#include <hip/hip_runtime.h>
#include <math.h>

#define B_   4
#define N_   512
#define DIN  256
#define E_   64
#define H_   4
#define QT_  8      // q rows per attn block

// ---------------------------------------------------------------------------
// Projection kernel: per block computes Y[32 rows][64 cols] = X_tile * W + b
// grid = B*H*3*(N/32) = 768 blocks, 256 threads (3 blocks/CU).
// p=0 -> Q [B][H][N][E], p=1 -> KT [B][H][E][N] (transposed), p=2 -> V.
// ---------------------------------------------------------------------------
__global__ __launch_bounds__(256) void proj_kernel(
    const float* __restrict__ x,
    const float* __restrict__ Wq, const float* __restrict__ bq,
    const float* __restrict__ Wk, const float* __restrict__ bk,
    const float* __restrict__ Wv, const float* __restrict__ bv,
    float* __restrict__ Q, float* __restrict__ KT, float* __restrict__ V)
{
    const int tid = threadIdx.x;
    int blk = blockIdx.x;
    const int tile = blk & 15;  blk >>= 4;
    const int p    = blk % 3;   blk /= 3;
    const int h    = blk & 3;
    const int b    = blk >> 2;

    const float* W;
    const float* bias;
    if (p == 0)      { W = Wq; bias = bq; }
    else if (p == 1) { W = Wk; bias = bk; }
    else             { W = Wv; bias = bv; }
    W    += (size_t)h * DIN * E_;
    bias += h * E_;

    const int rowbase = tile * 32;
    const float* xb = x + ((size_t)b * N_ + rowbase) * DIN;

    __shared__ float XsT[64][34];   // [d][r] transposed; stride 34 -> aligned float2
    __shared__ float Ws[64][68];    // +4 pad keeps float4 alignment

    const int tr = tid >> 4;   // 0..15 -> rows tr*2, tr*2+1
    const int tc = tid & 15;   // 0..15 -> cols tc*4..tc*4+3

    float acc[2][4];
    #pragma unroll
    for (int i = 0; i < 2; ++i)
        #pragma unroll
        for (int j = 0; j < 4; ++j) acc[i][j] = 0.f;

    for (int dc = 0; dc < DIN; dc += 64) {
        for (int l = tid; l < 2048; l += 256) {     // 32 rows x 64 d
            int r = l >> 6, d = l & 63;
            XsT[d][r] = xb[r * DIN + dc + d];
        }
        for (int l = tid; l < 4096; l += 256) {     // 64 d x 64 cols
            int d = l >> 6, c = l & 63;
            Ws[d][c] = W[(size_t)(dc + d) * E_ + c];
        }
        __syncthreads();

        #pragma unroll 8
        for (int d = 0; d < 64; ++d) {
            float2 xv = *(const float2*)&XsT[d][tr * 2];
            float4 wv = *(const float4*)&Ws[d][tc * 4];
            acc[0][0] = fmaf(xv.x, wv.x, acc[0][0]);
            acc[0][1] = fmaf(xv.x, wv.y, acc[0][1]);
            acc[0][2] = fmaf(xv.x, wv.z, acc[0][2]);
            acc[0][3] = fmaf(xv.x, wv.w, acc[0][3]);
            acc[1][0] = fmaf(xv.y, wv.x, acc[1][0]);
            acc[1][1] = fmaf(xv.y, wv.y, acc[1][1]);
            acc[1][2] = fmaf(xv.y, wv.z, acc[1][2]);
            acc[1][3] = fmaf(xv.y, wv.w, acc[1][3]);
        }
        __syncthreads();
    }

    const size_t bh = (size_t)b * H_ + h;
    float4 bias4 = *(const float4*)&bias[tc * 4];

    if (p == 1) {
        // K transposed: KT[b][h][e][n]
        float* o = KT + bh * (size_t)(E_ * N_);
        #pragma unroll
        for (int i = 0; i < 2; ++i) {
            int r = rowbase + tr * 2 + i;
            o[(size_t)(tc * 4 + 0) * N_ + r] = acc[i][0] + bias4.x;
            o[(size_t)(tc * 4 + 1) * N_ + r] = acc[i][1] + bias4.y;
            o[(size_t)(tc * 4 + 2) * N_ + r] = acc[i][2] + bias4.z;
            o[(size_t)(tc * 4 + 3) * N_ + r] = acc[i][3] + bias4.w;
        }
    } else {
        float* o = (p == 0 ? Q : V) + bh * (size_t)(N_ * E_);
        #pragma unroll
        for (int i = 0; i < 2; ++i) {
            int r = rowbase + tr * 2 + i;
            float4 val;
            val.x = acc[i][0] + bias4.x;
            val.y = acc[i][1] + bias4.y;
            val.z = acc[i][2] + bias4.z;
            val.w = acc[i][3] + bias4.w;
            *(float4*)&o[(size_t)r * E_ + tc * 4] = val;
        }
    }
}

// ---------------------------------------------------------------------------
// Attention kernel: per block one (b, h, 8-row q tile). grid = 1024 blocks
// (4 blocks/CU, 16 waves/CU). LDS ~22 KB.
// ---------------------------------------------------------------------------
template <int HEAD>
__device__ __forceinline__ void compute_logits(
    const float* __restrict__ KTbh, const float (*q_lds)[16],
    float (*P)[512], const float* __restrict__ kn, const float* __restrict__ qn,
    int tid)
{
    float acc0[QT_], acc1[QT_];
    #pragma unroll
    for (int r = 0; r < QT_; ++r) { acc0[r] = 0.f; acc1[r] = 0.f; }

    const int m0 = tid;
    const int m1 = tid + 256;

    #pragma unroll 4
    for (int e = 0; e < 64; ++e) {
        float k0 = KTbh[e * N_ + m0];
        float k1 = KTbh[e * N_ + m1];
        float4 qa = *(const float4*)&q_lds[e][0];
        float4 qb = *(const float4*)&q_lds[e][4];
        float qv[QT_] = {qa.x, qa.y, qa.z, qa.w, qb.x, qb.y, qb.z, qb.w};
        #pragma unroll
        for (int r = 0; r < QT_; ++r) {
            if (HEAD <= 1) {          // dot product (sdp / cosine)
                acc0[r] = fmaf(qv[r], k0, acc0[r]);
                acc1[r] = fmaf(qv[r], k1, acc1[r]);
            } else if (HEAD == 2) {   // L1
                acc0[r] += fabsf(k0 - qv[r]);
                acc1[r] += fabsf(k1 - qv[r]);
            } else {                  // L2 (squared, sqrt at the end)
                float d0 = k0 - qv[r]; acc0[r] = fmaf(d0, d0, acc0[r]);
                float d1 = k1 - qv[r]; acc1[r] = fmaf(d1, d1, acc1[r]);
            }
        }
    }

    float ikn0 = 0.f, ikn1 = 0.f;
    if (HEAD == 1) { ikn0 = kn[m0]; ikn1 = kn[m1]; }  // inverse norms
    #pragma unroll
    for (int r = 0; r < QT_; ++r) {
        float l0, l1;
        if (HEAD == 0)      { l0 = acc0[r] * 0.125f;        l1 = acc1[r] * 0.125f; }
        else if (HEAD == 1) { float iq = qn[r];
                              l0 = acc0[r] * iq * ikn0;     l1 = acc1[r] * iq * ikn1; }
        else if (HEAD == 2) { l0 = -acc0[r];                l1 = -acc1[r]; }
        else                { l0 = -sqrtf(acc0[r]);         l1 = -sqrtf(acc1[r]); }
        P[r][m0] = l0;
        P[r][m1] = l1;
    }
}

__global__ __launch_bounds__(256) void attn_kernel(
    const float* __restrict__ Q, const float* __restrict__ KT,
    const float* __restrict__ V, float* __restrict__ out)
{
    const int tid = threadIdx.x;
    int blk = blockIdx.x;
    const int qt = blk & 63; blk >>= 6;
    const int h  = blk & 3;
    const int b  = blk >> 2;

    const size_t bh = (size_t)b * H_ + h;
    const float* Qbh  = Q  + bh * (size_t)(N_ * E_) + (size_t)qt * QT_ * E_;
    const float* KTbh = KT + bh * (size_t)(E_ * N_);
    const float* Vbh  = V  + bh * (size_t)(N_ * E_);

    __shared__ float q_lds[64][16];   // [e][r], 64B stride: aligned float4 reads
    __shared__ float P[QT_][512];
    __shared__ float kn[512];
    __shared__ float qn[QT_];
    __shared__ float rinv[QT_];

    // stage q transposed into LDS (coalesced global read)
    for (int l = tid; l < QT_ * 64; l += 256) {
        int r = l >> 6, e = l & 63;
        q_lds[e][r] = Qbh[l];
    }
    __syncthreads();

    if (h == 1) {  // inverse norms for cosine head (block-uniform branch)
        if (tid < QT_) {
            float s = 0.f;
            for (int e = 0; e < 64; ++e) { float v = q_lds[e][tid]; s = fmaf(v, v, s); }
            qn[tid] = 1.f / sqrtf(s);
        }
        for (int m = tid; m < 512; m += 256) {
            float s = 0.f;
            #pragma unroll 4
            for (int e = 0; e < 64; ++e) { float t = KTbh[e * N_ + m]; s = fmaf(t, t, s); }
            kn[m] = 1.f / sqrtf(s);
        }
        __syncthreads();
    }

    if (h == 0)      compute_logits<0>(KTbh, q_lds, P, kn, qn, tid);
    else if (h == 1) compute_logits<1>(KTbh, q_lds, P, kn, qn, tid);
    else if (h == 2) compute_logits<2>(KTbh, q_lds, P, kn, qn, tid);
    else             compute_logits<3>(KTbh, q_lds, P, kn, qn, tid);
    __syncthreads();

    // softmax: wave wv owns rows wv*2, wv*2+1
    {
        const int wv = tid >> 6, lane = tid & 63;
        #pragma unroll
        for (int rr = 0; rr < 2; ++rr) {
            int r = wv * 2 + rr;
            float vals[8];
            float mx = -1e30f;
            #pragma unroll
            for (int k = 0; k < 8; ++k) {
                vals[k] = P[r][lane + k * 64];
                mx = fmaxf(mx, vals[k]);
            }
            #pragma unroll
            for (int off = 32; off; off >>= 1) mx = fmaxf(mx, __shfl_xor(mx, off, 64));
            float s = 0.f;
            #pragma unroll
            for (int k = 0; k < 8; ++k) {
                float pv = __expf(vals[k] - mx);
                s += pv;
                P[r][lane + k * 64] = pv;
            }
            #pragma unroll
            for (int off = 32; off; off >>= 1) s += __shfl_xor(s, off, 64);
            if (lane == 0) rinv[r] = 1.f / s;
        }
    }
    __syncthreads();

    // PV: thread -> (2 rows, one e). P reads are wave-broadcast, V coalesced.
    {
        const int rgrp = tid >> 6;
        const int e    = tid & 63;
        const int r0 = rgrp * 2, r1 = r0 + 1;
        float a0 = 0.f, a1 = 0.f;

        for (int m = 0; m < N_; m += 4) {
            float v0 = Vbh[(size_t)(m + 0) * E_ + e];
            float v1 = Vbh[(size_t)(m + 1) * E_ + e];
            float v2 = Vbh[(size_t)(m + 2) * E_ + e];
            float v3 = Vbh[(size_t)(m + 3) * E_ + e];
            float4 p0 = *(const float4*)&P[r0][m];
            float4 p1 = *(const float4*)&P[r1][m];
            a0 = fmaf(p0.x, v0, a0); a0 = fmaf(p0.y, v1, a0);
            a0 = fmaf(p0.z, v2, a0); a0 = fmaf(p0.w, v3, a0);
            a1 = fmaf(p1.x, v0, a1); a1 = fmaf(p1.y, v1, a1);
            a1 = fmaf(p1.z, v2, a1); a1 = fmaf(p1.w, v3, a1);
        }

        const int n0 = qt * QT_ + r0;
        out[((size_t)b * N_ + n0) * (H_ * E_) + h * E_ + e]     = a0 * rinv[r0];
        out[((size_t)b * N_ + n0 + 1) * (H_ * E_) + h * E_ + e] = a1 * rinv[r1];
    }
}

// ---------------------------------------------------------------------------
extern "C" void kernel_launch(void* const* d_in, const int* in_sizes, int n_in,
                              void* d_out, int out_size, void* d_ws, size_t ws_size,
                              hipStream_t stream)
{
    const float* x  = (const float*)d_in[0];
    const float* Wq = (const float*)d_in[1];
    const float* bq = (const float*)d_in[2];
    const float* Wk = (const float*)d_in[3];
    const float* bk = (const float*)d_in[4];
    const float* Wv = (const float*)d_in[5];
    const float* bv = (const float*)d_in[6];
    float* out = (float*)d_out;

    float* ws = (float*)d_ws;
    const size_t qkv = (size_t)B_ * H_ * N_ * E_;  // 524288 floats
    float* Q  = ws;
    float* KT = ws + qkv;
    float* V  = ws + 2 * qkv;

    proj_kernel<<<B_ * H_ * 3 * (N_ / 32), 256, 0, stream>>>(
        x, Wq, bq, Wk, bk, Wv, bv, Q, KT, V);
    attn_kernel<<<B_ * H_ * (N_ / QT_), 256, 0, stream>>>(Q, KT, V, out);
}